// Round 8
// baseline (1906.806 us; speedup 1.0000x reference)
//
#include <hip/hip_runtime.h>
#include <hip/hip_bf16.h>

#define B_ 128
#define T_ 512
#define I_ 64
#define H_ 1024
#define O_ 12
#define HSTEP (H_ * B_)   // 131072 bf16 elements per timestep of hP
#define XSTEP (I_ * B_)   // 8192 bf16 elements per timestep of xPhi
#define RSLOT 16384       // shorts per ring slot: 128 kb-octets * 16 batches * 8
#define TIMEOUT 2000      // fast-flag poll rounds before sticky fallback

typedef __attribute__((ext_vector_type(8))) short bf16x8;
typedef __attribute__((ext_vector_type(4))) float f32x4;
typedef __attribute__((ext_vector_type(4))) unsigned u32x4;  // asm-safe 16B payload

#define MFMA16 __builtin_amdgcn_mfma_f32_16x16x32_bf16

__device__ __forceinline__ float bf2f(unsigned short s) {
  unsigned u = ((unsigned)s) << 16; float f; __builtin_memcpy(&f, &u, 4); return f;
}
__device__ __forceinline__ unsigned short f2bf(float f) {
  unsigned u; __builtin_memcpy(&u, &f, 4);
  u += 0x7fffu + ((u >> 16) & 1u);   // RNE (finite inputs only here)
  return (unsigned short)(u >> 16);
}

// ---- proven agent-scope (LLC) atomics ----
__device__ __forceinline__ unsigned ldA32(const unsigned* p) {
  return __hip_atomic_load(p, __ATOMIC_RELAXED, __HIP_MEMORY_SCOPE_AGENT);
}
__device__ __forceinline__ void stA32(unsigned* p, unsigned v) {
  __hip_atomic_store(p, v, __ATOMIC_RELAXED, __HIP_MEMORY_SCOPE_AGENT);
}
__device__ __forceinline__ unsigned long long ldA64(const unsigned long long* p) {
  return __hip_atomic_load(p, __ATOMIC_RELAXED, __HIP_MEMORY_SCOPE_AGENT);
}
__device__ __forceinline__ void stA64(unsigned long long* p, unsigned long long v) {
  __hip_atomic_store(p, v, __ATOMIC_RELAXED, __HIP_MEMORY_SCOPE_AGENT);
}

// ---- XCD-local primitives (sc0: bypass L1, served by this XCD's L2) ----
// Speed-only: every use has a proven-slow dual; never load-bearing for
// correctness or termination. NOTE: asm "v" operands must be scalar or
// ext_vector types (HIP uint4 is a struct -> compile error).
__device__ __forceinline__ void store32_sc0(unsigned* p, unsigned v) {
  asm volatile("global_store_dword %0, %1, off sc0" :: "v"(p), "v"(v) : "memory");
}
__device__ __forceinline__ void store16_sc0(void* p, u32x4 v) {
  asm volatile("global_store_dwordx4 %0, %1, off sc0" :: "v"(p), "v"(v) : "memory");
}
__device__ __forceinline__ unsigned poll_sc0(const unsigned* p) {
  unsigned v;
  asm volatile("global_load_dword %0, %1, off sc0\n\ts_waitcnt vmcnt(0)"
               : "=v"(v) : "v"(p) : "memory");
  return v;
}
__device__ __forceinline__ bf16x8 load16_sc0(const void* p) {
  bf16x8 v;
  asm volatile("global_load_dwordx4 %0, %1, off sc0" : "=v"(v) : "v"(p));
  return v;
}
__device__ __forceinline__ void waitv8(bf16x8& v0, bf16x8& v1, bf16x8& v2, bf16x8& v3,
                                       bf16x8& v4, bf16x8& v5, bf16x8& v6, bf16x8& v7) {
  asm volatile("s_waitcnt vmcnt(0)"
               : "+v"(v0), "+v"(v1), "+v"(v2), "+v"(v3),
                 "+v"(v4), "+v"(v5), "+v"(v6), "+v"(v7) :: "memory");
}
__device__ __forceinline__ void vmwait0() {
  asm volatile("s_waitcnt vmcnt(0)" ::: "memory");
}

// ---- prep: x[b][t][i] fp32 -> pack-layout bf16 plane xPhi[t][i/8][b][i%8] ----
__global__ void prep_xp(const float* __restrict__ x,
                        unsigned short* __restrict__ xPhi) {
  const int t = blockIdx.x;
  for (int u = threadIdx.x; u < 1024; u += 256) {   // u = ib*128 + b
    const int ib = u >> 7, b = u & 127;
    const float* src = x + ((size_t)b * T_ + t) * I_ + ib * 8;
    bf16x8 hi;
    #pragma unroll
    for (int j = 0; j < 8; ++j) hi[j] = (short)f2bf(src[j]);
    *(bf16x8*)(xPhi + ((size_t)t * 1024 + u) * 8) = hi;
  }
}

// ---- prep: zero flags + W_out transposed/padded WoT[k][16] ----
// bar uints: [0..255] fast flags (sc0 medium), [256..511] slow flags (LLC).
__global__ void prep_misc(const float* __restrict__ W_out, float* __restrict__ WoT,
                          unsigned* __restrict__ bar) {
  const int idx = blockIdx.x * 256 + threadIdx.x;   // 64 blocks -> 16384 threads
  if (idx < 1024) bar[idx] = 0u;
  const int k = idx >> 4, s = idx & 15;
  float v = 0.0f;
  if (s < 6)                 v = W_out[s * H_ + k];
  else if (s >= 8 && s < 14) v = W_out[(s - 2) * H_ + k];
  WoT[idx] = v;
}

// ---- persistent MFMA recurrence ----
// g = bid&7 (batch group; XCD-pure under round-robin dispatch), rg = bid>>3.
// h_t staged in LDS, then wave-specialized publish (vmcnt is PER-WAVE, so the
// fast flag waits only on the fast-ring stores):
//   wave0: rF dense 16B sc0 stores -> vmcnt0 -> fast flag -> computeX(t+1)
//   wave1: rS dense 8B agent atomics -> vmcnt0 -> slow flag -> computeX(t+1)
//   wave2: hP history dense 16B cached stores (full lines: no write-allocate)
//   wave3: bounded fast poll, sticky per-block fallback to proven slow path.
__global__ __launch_bounds__(256, 1) void rnn_mfma(
    const float* __restrict__ W_ih, const float* __restrict__ W_hh,
    const float* __restrict__ b_ih, const float* __restrict__ b_hh,
    const unsigned short* __restrict__ xPhi, unsigned short* __restrict__ hP,
    unsigned short* __restrict__ rF, unsigned short* __restrict__ rS,
    unsigned* __restrict__ bar)
{
  __shared__ float part[4][544];    // 8 rows x 68 (padded)
  __shared__ unsigned stage[256];   // h_t dense: [kb][n][jj] uints (1 KB)
  __shared__ float biasS[32];
  __shared__ unsigned modeS;        // 1 = fast, one-way latch to 0
  const int tid = threadIdx.x, bid = blockIdx.x;
  const int wave = tid >> 6, lane = tid & 63, quad = lane >> 4, ln = lane & 15;
  const int g = bid & 7, rg = bid >> 3;
  const int r0 = rg * 32, b0 = g * 16;
  if (tid < 32) biasS[tid] = b_ih[r0 + tid] + b_hh[r0 + tid];
  if (tid == 0) modeS = 1u;

  // A-frags for W_hh (hi/lo split -> fp32-grade W precision), loaded once.
  bf16x8 ahhi[2][8], ahlo[2][8];
  #pragma unroll
  for (int mt = 0; mt < 2; ++mt)
    #pragma unroll
    for (int kt = 0; kt < 8; ++kt) {
      const float* wp = W_hh + (size_t)(r0 + mt * 16 + ln) * H_
                        + wave * 256 + kt * 32 + quad * 8;
      #pragma unroll
      for (int j = 0; j < 8; ++j) {
        float v = wp[j];
        unsigned short h = f2bf(v);
        ahhi[mt][kt][j] = (short)h;
        ahlo[mt][kt][j] = (short)f2bf(v - bf2f(h));
      }
    }
  // A-frags for W_ih: waves 0,1 own the two x K-tiles (i in [32w,32w+32)).
  bf16x8 axhi[2], axlo[2];
  if (wave < 2)
    #pragma unroll
    for (int mt = 0; mt < 2; ++mt) {
      const float* wp = W_ih + (size_t)(r0 + mt * 16 + ln) * I_
                        + wave * 32 + quad * 8;
      #pragma unroll
      for (int j = 0; j < 8; ++j) {
        float v = wp[j];
        unsigned short h = f2bf(v);
        axhi[mt][j] = (short)h;
        axlo[mt][j] = (short)f2bf(v - bf2f(h));
      }
    }
  __syncthreads();
  unsigned mode = 1u;               // block-uniform; updated only after barriers

  const int bcol = b0 + ln;
  unsigned short* rFg = rF + (size_t)g * 2 * RSLOT;
  unsigned short* rSg = rS + (size_t)g * 2 * RSLOT;

  f32x4 xacc0 = {0.f, 0.f, 0.f, 0.f}, xacc1 = {0.f, 0.f, 0.f, 0.f};
  auto computeX = [&](int t) {      // x-contribution for step t (waves 0,1)
    if (wave < 2) {
      const size_t xo = (((size_t)t * 8 + wave * 4 + quad) * B_ + bcol) * 8;
      bf16x8 bxh = *(const bf16x8*)(xPhi + xo);
      f32x4 t0 = {0.f, 0.f, 0.f, 0.f}, t1 = {0.f, 0.f, 0.f, 0.f};
      t0 = MFMA16(axhi[0], bxh, t0, 0, 0, 0);
      t0 = MFMA16(axlo[0], bxh, t0, 0, 0, 0);
      t1 = MFMA16(axhi[1], bxh, t1, 0, 0, 0);
      t1 = MFMA16(axlo[1], bxh, t1, 0, 0, 0);
      xacc0 = t0; xacc1 = t1;
    }
  };
  computeX(0);

  for (int t = 0; t < T_; ++t) {
    f32x4 accA0 = xacc0, accA1 = xacc1;                       // hi-chain
    f32x4 accB0 = {0.f, 0.f, 0.f, 0.f}, accB1 = {0.f, 0.f, 0.f, 0.f}; // lo-chain

    if (t > 0) {
      const int soff = ((wave * 32 + quad) * 16 + ln) * 8;    // shorts
      bf16x8 bh[8];
      if (mode) {
        const unsigned short* slot = rFg + ((t - 1) & 1) * RSLOT + soff;
        #pragma unroll
        for (int kt = 0; kt < 8; ++kt)
          bh[kt] = load16_sc0(slot + kt * 512);               // XCD-L2 hits
        waitv8(bh[0], bh[1], bh[2], bh[3], bh[4], bh[5], bh[6], bh[7]);
      } else {
        const unsigned long long* slot =
            (const unsigned long long*)(rSg + ((t - 1) & 1) * RSLOT + soff);
        #pragma unroll
        for (int kt = 0; kt < 8; ++kt) {
          union { unsigned long long u[2]; bf16x8 v; } U;
          U.u[0] = ldA64(slot + kt * 128);
          U.u[1] = ldA64(slot + kt * 128 + 1);
          bh[kt] = U.v;
        }
      }
      #pragma unroll
      for (int kt = 0; kt < 8; ++kt) {
        accA0 = MFMA16(ahhi[0][kt], bh[kt], accA0, 0, 0, 0);
        accA1 = MFMA16(ahhi[1][kt], bh[kt], accA1, 0, 0, 0);
        accB0 = MFMA16(ahlo[0][kt], bh[kt], accB0, 0, 0, 0);
        accB1 = MFMA16(ahlo[1][kt], bh[kt], accB1, 0, 0, 0);
      }
    }

    // combine K-split partials across waves via LDS (rows padded to 68)
    #pragma unroll
    for (int r = 0; r < 4; ++r) {
      part[wave][r * 68 + lane]       = accA0[r] + accB0[r];
      part[wave][(4 + r) * 68 + lane] = accA1[r] + accB1[r];
    }
    __syncthreads();

    // epilogue: 256 threads, 2 rows each -> dense LDS stage
    {
      const int n = tid & 15, rp = tid >> 4;
      const int m0 = rp * 2;
      unsigned short o[2];
      #pragma unroll
      for (int rr = 0; rr < 2; ++rr) {
        const int m = m0 + rr;
        const int f = ((m >> 4) * 4 + (m & 3)) * 68 + ((m >> 2) & 3) * 16 + n;
        float s = part[0][f] + part[1][f] + part[2][f] + part[3][f] + biasS[m];
        o[rr] = f2bf(tanhf(s));
      }
      stage[(rp >> 2) * 64 + n * 4 + (rp & 3)] =
          (unsigned)o[0] | ((unsigned)o[1] << 16);
    }
    __syncthreads();

    // wave-specialized publish + group barrier (per-wave vmcnt isolation)
    const int slotoff = (t & 1) * RSLOT;
    if (wave == 0) {                       // fast ring + fast flag
      u32x4 v = *(const u32x4*)&stage[lane * 4];
      store16_sc0(rFg + slotoff + rg * 512 + lane * 8, v);
      vmwait0();                           // waits ONLY wave0's rF store
      if (lane == 0 && t < T_ - 1) store32_sc0(&bar[g * 32 + rg], (unsigned)(t + 1));
      if (t < T_ - 1) computeX(t + 1);     // hidden under wave3's poll
    } else if (wave == 1) {                // slow ring + slow flag (proven medium)
      const unsigned long long* s = (const unsigned long long*)&stage[lane * 4];
      unsigned long long* d =
          (unsigned long long*)(rSg + slotoff + rg * 512) + lane * 2;
      stA64(d, s[0]); stA64(d + 1, s[1]);
      vmwait0();
      if (lane == 0 && t < T_ - 1) stA32(&bar[256 + g * 32 + rg], (unsigned)(t + 1));
      if (t < T_ - 1) computeX(t + 1);
    } else if (wave == 2) {                // history for out_proj (full lines)
      u32x4 v = *(const u32x4*)&stage[lane * 4];
      *(u32x4*)(hP + (size_t)t * HSTEP
                + ((size_t)(rg * 4 + (lane >> 4)) * B_ + b0 + (lane & 15)) * 8) = v;
      vmwait0();
    } else if (t < T_ - 1) {               // wave 3: barrier poll
      int ok = 0;
      if (mode) {
        for (int it = 0; it < TIMEOUT && !ok; ++it) {
          unsigned v = (lane < 32) ? poll_sc0(&bar[g * 32 + lane]) : 0xffffffffu;
          ok = __all((int)(v >= (unsigned)(t + 1)));
        }
      }
      if (!ok) {                           // sticky fallback to proven LLC path
        if (lane == 0) modeS = 0u;
        for (;;) {
          unsigned v = (lane < 32) ? ldA32(&bar[256 + g * 32 + lane]) : 0xffffffffu;
          if (__all((int)(v >= (unsigned)(t + 1)))) break;
          __builtin_amdgcn_s_sleep(1);
        }
      }
    }
    __syncthreads();                       // releases block; guards part/stage reuse
    mode = modeS;
  }
}

// ---- output projection from pack layout: out[b][t][o] ----
__global__ __launch_bounds__(256, 2) void out_proj(
    const unsigned short* __restrict__ hP, const float* __restrict__ WoT,
    const float* __restrict__ b_out, float* __restrict__ out)
{
  const int t = blockIdx.x;
  const int tid = threadIdx.x;
  const int b  = tid & 127;
  const int oh = tid >> 7;                 // wave-uniform output half
  float a0 = b_out[oh * 6 + 0], a1 = b_out[oh * 6 + 1], a2 = b_out[oh * 6 + 2];
  float a3 = b_out[oh * 6 + 3], a4 = b_out[oh * 6 + 4], a5 = b_out[oh * 6 + 5];
  const unsigned short* hp = hP + (size_t)t * HSTEP + (size_t)b * 8;
  const float4* W4 = (const float4*)WoT;
  for (int kb = 0; kb < 128; ++kb) {
    bf16x8 hv = *(const bf16x8*)(hp + (size_t)kb * (B_ * 8));  // 16B coalesced
    #pragma unroll
    for (int j = 0; j < 8; ++j) {
      const int k = kb * 8 + j;
      float h = bf2f((unsigned short)hv[j]);
      float4 wa = W4[k * 4 + oh * 2];       // wave-uniform
      float4 wb = W4[k * 4 + oh * 2 + 1];
      a0 += wa.x * h; a1 += wa.y * h; a2 += wa.z * h;
      a3 += wa.w * h; a4 += wb.x * h; a5 += wb.y * h;
    }
  }
  float* op = out + ((size_t)b * T_ + t) * O_ + oh * 6;
  op[0] = a0; op[1] = a1; op[2] = a2; op[3] = a3; op[4] = a4; op[5] = a5;
}

// ---- host ----
extern "C" void kernel_launch(void* const* d_in, const int* in_sizes, int n_in,
                              void* d_out, int out_size, void* d_ws, size_t ws_size,
                              hipStream_t stream)
{
  const float* x     = (const float*)d_in[0];
  const float* W_ih  = (const float*)d_in[1];
  const float* W_hh  = (const float*)d_in[2];
  const float* b_ih  = (const float*)d_in[3];
  const float* b_hh  = (const float*)d_in[4];
  const float* W_out = (const float*)d_in[5];
  const float* b_out = (const float*)d_in[6];
  float* out = (float*)d_out;

  unsigned short* hP   = (unsigned short*)d_ws;                  // 134.2 MB
  unsigned short* xPhi = hP + (size_t)T_ * HSTEP;                // 8.4 MB
  float*          WoT  = (float*)(xPhi + (size_t)T_ * XSTEP);    // 64 KB
  unsigned short* rF   = (unsigned short*)(WoT + (size_t)H_ * 16); // 512 KB
  unsigned short* rS   = rF + (size_t)8 * 2 * RSLOT;             // 512 KB
  unsigned*       bar  = (unsigned*)(rS + (size_t)8 * 2 * RSLOT); // 4 KB

  prep_xp  <<<T_,  256, 0, stream>>>(x, xPhi);
  prep_misc<<<64,  256, 0, stream>>>(W_out, WoT, bar);
  rnn_mfma <<<256, 256, 0, stream>>>(W_ih, W_hh, b_ih, b_hh, xPhi, hP, rF, rS, bar);
  out_proj <<<T_,  256, 0, stream>>>(hP, WoT, b_out, out);
}